// Round 3
// baseline (588.908 us; speedup 1.0000x reference)
//
#include <hip/hip_runtime.h>
#include <hip/hip_bf16.h>

// INT8 dynamic-quant GEMM: out = (x_int8 @ w_int8^T) * (x_scales * w_scales^T)
// x: [M,K] f32, w: [N,K] f32, out: [M,N] f32.  M=8192, K=4096, N=11008.

#define QEPS 1e-5f

using int4v = __attribute__((ext_vector_type(4))) int;

typedef __attribute__((address_space(3))) signed char lds_i8_t;
typedef __attribute__((address_space(1))) const signed char glb_i8_t;

// ---------------- per-row absmax quantize (K = 4096 fixed) ----------------
__global__ __launch_bounds__(256) void quant_rows_k(const float* __restrict__ in,
                                                    signed char* __restrict__ out8,
                                                    float* __restrict__ scales) {
    const int K = 4096;
    const int row = blockIdx.x;
    const int t = threadIdx.x;
    const float4* in4 = (const float4*)(in + (size_t)row * K);
    float4 v[4];
    float amax = 0.f;
#pragma unroll
    for (int j = 0; j < 4; ++j) {
        v[j] = in4[t + 256 * j];
        amax = fmaxf(amax, fmaxf(fmaxf(fabsf(v[j].x), fabsf(v[j].y)),
                                 fmaxf(fabsf(v[j].z), fabsf(v[j].w))));
    }
#pragma unroll
    for (int off = 32; off > 0; off >>= 1)
        amax = fmaxf(amax, __shfl_xor(amax, off));
    __shared__ float wmax[4];
    if ((t & 63) == 0) wmax[t >> 6] = amax;
    __syncthreads();
    amax = fmaxf(fmaxf(wmax[0], wmax[1]), fmaxf(wmax[2], wmax[3]));
    const float scale = fmaxf(amax, QEPS) / 127.0f;
    if (t == 0) scales[row] = scale;
    char4* o4 = (char4*)(out8 + (size_t)row * K);
#pragma unroll
    for (int j = 0; j < 4; ++j) {
        char4 q;
        q.x = (signed char)(int)rintf(v[j].x / scale);  // rintf = round-half-even = jnp.round
        q.y = (signed char)(int)rintf(v[j].y / scale);
        q.z = (signed char)(int)rintf(v[j].z / scale);
        q.w = (signed char)(int)rintf(v[j].w / scale);
        o4[t + 256 * j] = q;
    }
}

// ---------------- int8 GEMM, 256x256 tile, 8-phase pipelined schedule ----
// K-tile = 128 i8 (128 B/row). Each K-tile split into 2 K-halves of 64 B;
// LDS layout [buf][ks][row][64] -> fragment ds_read_b128 is naturally 2-way
// banked (free), no swizzle needed, global_load_lds stays linear.
// Per tile u (buf=u&1): 4 phases (ks,mh); each phase = {ds_read frags;
// stage 1 half of tile u+1 into buf^1; [vmcnt(4) at phases 1,3]; barrier;
// setprio(1); 16 MFMA; setprio(0); barrier}.  Halves staged in consumption
// order, 4-phase lead; vmcnt never drains to 0 (T3+T4), setprio active (T5),
// bijective XCD swizzle (T1).
__global__ __launch_bounds__(512, 2) void gemm_i8_8ph(const signed char* __restrict__ A,
                                                      const signed char* __restrict__ B,
                                                      const float* __restrict__ xs,
                                                      const float* __restrict__ wsc,
                                                      float* __restrict__ C) {
    constexpr int K = 4096;
    constexpr int N = 11008;
    constexpr int NT = 32;           // K / 128
    constexpr int HALF = 256 * 64;   // 16 KB per half

    __shared__ __align__(16) signed char lsA[2][2 * HALF];  // [buf][ks*HALF + row*64 + c]
    __shared__ __align__(16) signed char lsB[2][2 * HALF];

    const int t = threadIdx.x;
    const int lane = t & 63;
    const int wid = t >> 6;
    const int wr = wid >> 2;   // 0..1 -> 128 rows
    const int wc = wid & 3;    // 0..3 -> 64 cols

    // XCD-aware swizzle: grid 1376 = 8 XCDs x 172 (bijective)
    const int wg = (blockIdx.x & 7) * ((int)gridDim.x >> 3) + ((int)blockIdx.x >> 3);
    const int by = wg / 43;
    const int bx = wg - by * 43;
    const int brow = by * 256;
    const int bcol = bx * 256;

    // staging: per half, chunk = i*512 + t (i=0,1); row = chunk>>2, c16 = chunk&3
    const int srow = t >> 2;          // 0..127 (+128 for i=1)
    const int sc = (t & 3) * 16;
    const signed char* aSrc0 = A + (size_t)(brow + srow) * K + sc;
    const signed char* aSrc1 = aSrc0 + (size_t)128 * K;
    const signed char* bSrc0 = B + (size_t)(bcol + srow) * K + sc;
    const signed char* bSrc1 = bSrc0 + (size_t)128 * K;

    // fragment geometry (mfma_i32_16x16x64_i8): row = lane&15, k-grp = (lane>>4)*16
    const int arow0 = wr * 128 + (lane & 15);
    const int bcol0 = wc * 64 + (lane & 15);
    const int kgrp = (lane >> 4) * 16;

    int4v acc[8][4];
#pragma unroll
    for (int m = 0; m < 8; ++m)
#pragma unroll
        for (int n = 0; n < 4; ++n) acc[m][n] = (int4v){0, 0, 0, 0};

#define STAGE2(DST, S0, S1, OFFK)                                                         \
    do {                                                                                  \
        __builtin_amdgcn_global_load_lds((glb_i8_t*)((S0) + (OFFK)),                      \
                                         (lds_i8_t*)((DST) + t * 16), 16, 0, 0);          \
        __builtin_amdgcn_global_load_lds((glb_i8_t*)((S1) + (OFFK)),                      \
                                         (lds_i8_t*)((DST) + 8192 + t * 16), 16, 0, 0);   \
    } while (0)

    // prologue: stage tile 0 (4 halves, consumption order) into buf0
    {
        signed char* SA = &lsA[0][0];
        signed char* SB = &lsB[0][0];
        STAGE2(SA, aSrc0, aSrc1, 0);
        STAGE2(SB, bSrc0, bSrc1, 0);
        STAGE2(SA + HALF, aSrc0, aSrc1, 64);
        STAGE2(SB + HALF, bSrc0, bSrc1, 64);
        asm volatile("s_waitcnt vmcnt(4)" ::: "memory");  // K0 halves landed; K1 in flight
        __builtin_amdgcn_s_barrier();
    }

    int4v bf[4];

#define PHASE(KS, MH, SDST, S0, S1, SOFFK, DOVM)                                          \
    do {                                                                                  \
        const signed char* BAks = BA + (KS)*HALF;                                         \
        const signed char* BBks = BB + (KS)*HALF;                                         \
        if ((MH) == 0) {                                                                  \
            _Pragma("unroll") for (int n = 0; n < 4; ++n)                                 \
                bf[n] = *(const int4v*)(BBks + (bcol0 + n * 16) * 64 + kgrp);             \
        }                                                                                 \
        int4v af[4];                                                                      \
        _Pragma("unroll") for (int mi = 0; mi < 4; ++mi)                                  \
            af[mi] = *(const int4v*)(BAks + (arow0 + (MH)*64 + mi * 16) * 64 + kgrp);     \
        STAGE2((SDST), (S0), (S1), (SOFFK));                                              \
        if (DOVM) asm volatile("s_waitcnt vmcnt(4)" ::: "memory");                        \
        __builtin_amdgcn_s_barrier();                                                     \
        __builtin_amdgcn_s_setprio(1);                                                    \
        _Pragma("unroll") for (int mi = 0; mi < 4; ++mi)                                  \
            _Pragma("unroll") for (int n = 0; n < 4; ++n)                                 \
                acc[(MH)*4 + mi][n] = __builtin_amdgcn_mfma_i32_16x16x64_i8(              \
                    af[mi], bf[n], acc[(MH)*4 + mi][n], 0, 0, 0);                         \
        __builtin_amdgcn_s_setprio(0);                                                    \
        __builtin_amdgcn_s_barrier();                                                     \
    } while (0)

#pragma unroll 1
    for (int u = 0; u < NT; ++u) {
        const int buf = u & 1;
        const signed char* BA = &lsA[buf][0];
        const signed char* BB = &lsB[buf][0];
        signed char* SA = &lsA[buf ^ 1][0];
        signed char* SB = &lsB[buf ^ 1][0];
        const size_t off0 = (size_t)((u + 1) & (NT - 1)) * 128;  // wrap: redundant restage at tail

        PHASE(0, 0, SA, aSrc0, aSrc1, off0, 0);
        PHASE(0, 1, SB, bSrc0, bSrc1, off0, 1);
        PHASE(1, 0, SA + HALF, aSrc0, aSrc1, off0 + 64, 0);
        PHASE(1, 1, SB + HALF, bSrc0, bSrc1, off0 + 64, 1);
    }
#undef PHASE
#undef STAGE2

    // epilogue: C/D frag layout col=lane&15, row=(lane>>4)*4+reg
    const int rgrp = (lane >> 4) * 4;
    float wsv[4];
#pragma unroll
    for (int n = 0; n < 4; ++n) wsv[n] = wsc[bcol + wc * 64 + n * 16 + (lane & 15)];
#pragma unroll
    for (int m = 0; m < 8; ++m) {
#pragma unroll
        for (int r = 0; r < 4; ++r) {
            const int row = brow + wr * 128 + m * 16 + rgrp + r;
            const float xsv = xs[row];
            const size_t base = (size_t)row * N + bcol + wc * 64 + (lane & 15);
#pragma unroll
            for (int n = 0; n < 4; ++n)
                C[base + n * 16] = (float)acc[m][n][r] * (xsv * wsv[n]);
        }
    }
}

extern "C" void kernel_launch(void* const* d_in, const int* in_sizes, int n_in,
                              void* d_out, int out_size, void* d_ws, size_t ws_size,
                              hipStream_t stream) {
    const float* x = (const float*)d_in[0];
    const float* w = (const float*)d_in[1];
    float* out = (float*)d_out;

    const int K = 4096;
    const int M = in_sizes[0] / K;   // 8192
    const int N = in_sizes[1] / K;   // 11008

    signed char* x8 = (signed char*)d_ws;
    signed char* w8 = x8 + (size_t)M * K;
    float* xscales = (float*)(w8 + (size_t)N * K);
    float* wscales = xscales + M;

    quant_rows_k<<<M, 256, 0, stream>>>(x, x8, xscales);
    quant_rows_k<<<N, 256, 0, stream>>>(w, w8, wscales);
    const int nwg = (M / 256) * (N / 256);   // 32*43 = 1376 = 8*172
    gemm_i8_8ph<<<nwg, 512, 0, stream>>>(x8, w8, xscales, wscales, out);
}

// Round 4
// 554.265 us; speedup vs baseline: 1.0625x; 1.0625x over previous
//
#include <hip/hip_runtime.h>
#include <hip/hip_bf16.h>

// INT8 dynamic-quant GEMM: out = (x_int8 @ w_int8^T) * (x_scales * w_scales^T)
// x: [M,K] f32, w: [N,K] f32, out: [M,N] f32.  M=8192, K=4096, N=11008.

#define QEPS 1e-5f

using int4v = __attribute__((ext_vector_type(4))) int;

typedef __attribute__((address_space(3))) signed char lds_i8_t;
typedef __attribute__((address_space(1))) const signed char glb_i8_t;

// ---------------- per-row absmax quantize (K = 4096 fixed) ----------------
__global__ __launch_bounds__(256) void quant_rows_k(const float* __restrict__ in,
                                                    signed char* __restrict__ out8,
                                                    float* __restrict__ scales) {
    const int K = 4096;
    const int row = blockIdx.x;
    const int t = threadIdx.x;
    const float4* in4 = (const float4*)(in + (size_t)row * K);
    float4 v[4];
    float amax = 0.f;
#pragma unroll
    for (int j = 0; j < 4; ++j) {
        v[j] = in4[t + 256 * j];
        amax = fmaxf(amax, fmaxf(fmaxf(fabsf(v[j].x), fabsf(v[j].y)),
                                 fmaxf(fabsf(v[j].z), fabsf(v[j].w))));
    }
#pragma unroll
    for (int off = 32; off > 0; off >>= 1)
        amax = fmaxf(amax, __shfl_xor(amax, off));
    __shared__ float wmax[4];
    if ((t & 63) == 0) wmax[t >> 6] = amax;
    __syncthreads();
    amax = fmaxf(fmaxf(wmax[0], wmax[1]), fmaxf(wmax[2], wmax[3]));
    const float scale = fmaxf(amax, QEPS) / 127.0f;
    if (t == 0) scales[row] = scale;
    char4* o4 = (char4*)(out8 + (size_t)row * K);
#pragma unroll
    for (int j = 0; j < 4; ++j) {
        char4 q;
        q.x = (signed char)(int)rintf(v[j].x / scale);  // rintf = round-half-even = jnp.round
        q.y = (signed char)(int)rintf(v[j].y / scale);
        q.z = (signed char)(int)rintf(v[j].z / scale);
        q.w = (signed char)(int)rintf(v[j].w / scale);
        o4[t + 256 * j] = q;
    }
}

// ---------------- int8 GEMM, 256x256 tile, 8-phase, fragment-packed LDS ----
// LDS holds MFMA fragments contiguously in lane order: frag(16 rows x 64B) =
// 1024 B at fragIdx*1024, lane l's 16 B at lane*16. One global_load_lds
// stages exactly one fragment (HW dest = wave-uniform base + lane*16; the
// per-lane GLOBAL src computes the fragment element address). ds_read_b128
// at fragBase+lane*16 is perfectly linear -> zero bank conflicts, both sides.
// Frag index within a buffer: (ks*16 + rg)*1024, rg = row/16 (A) or col/16 (B).
// 8-phase schedule (T3+T4): per K-tile u, phases (ks,mh); each stages 1 unit
// (16 frags = 2 loads/thread) of tile u+1 in consumption order; vmcnt(4) at
// phases 1,3 (never 0); setprio around MFMA (T5); bijective XCD swizzle (T1).
__global__ __launch_bounds__(512, 2) void gemm_i8_fp(const signed char* __restrict__ A,
                                                     const signed char* __restrict__ B,
                                                     const float* __restrict__ xs,
                                                     const float* __restrict__ wsc,
                                                     float* __restrict__ C) {
    constexpr int K = 4096;
    constexpr int N = 11008;
    constexpr int NT = 32;            // K / 128
    constexpr int TILEB = 32768;      // 32 frags * 1024 B, per matrix per buffer

    __shared__ __align__(16) signed char lsA[2][TILEB];
    __shared__ __align__(16) signed char lsB[2][TILEB];

    const int t = threadIdx.x;
    const int lane = t & 63;
    const int wid = t >> 6;
    const int wr = wid >> 2;   // 0..1 -> 128 output rows
    const int wc = wid & 3;    // 0..3 -> 64 output cols

    // XCD-aware swizzle: grid 1376 = 8 XCDs x 172 (bijective)
    const int wg = (blockIdx.x & 7) * ((int)gridDim.x >> 3) + ((int)blockIdx.x >> 3);
    const int by = wg / 43;
    const int bx = wg - by * 43;
    const int brow = by * 256;
    const int bcol = bx * 256;

    // staging: wave `wid` stages frags rg = 2*wid, 2*wid+1 of each unit.
    // per-lane global src: row = rg*16 + (lane&15), kchunk = (lane>>4)*16
    const int fr = lane & 15;
    const int fc = (lane >> 4) * 16;
    const signed char* aSrc = A + (size_t)(brow + 2 * wid * 16 + fr) * K + fc;
    const signed char* bSrc = B + (size_t)(bcol + 2 * wid * 16 + fr) * K + fc;
    const int dstOff = 2 * wid * 1024 + lane * 16;

    int4v acc[8][4];
#pragma unroll
    for (int m = 0; m < 8; ++m)
#pragma unroll
        for (int n = 0; n < 4; ++n) acc[m][n] = (int4v){0, 0, 0, 0};

#define STAGEU(LSBASE, SRC, OFFK)                                                          \
    do {                                                                                   \
        __builtin_amdgcn_global_load_lds((glb_i8_t*)((SRC) + (size_t)(OFFK)),              \
                                         (lds_i8_t*)((LSBASE) + dstOff), 16, 0, 0);        \
        __builtin_amdgcn_global_load_lds((glb_i8_t*)((SRC) + (size_t)16 * K + (OFFK)),     \
                                         (lds_i8_t*)((LSBASE) + dstOff + 1024), 16, 0, 0); \
    } while (0)

    // prologue: stage tile 0 into buf0, consumption order: B-ks0, A-ks0, B-ks1, A-ks1
    STAGEU(&lsB[0][0], bSrc, 0);
    STAGEU(&lsA[0][0], aSrc, 0);
    STAGEU(&lsB[0][16384], bSrc, 64);
    STAGEU(&lsA[0][16384], aSrc, 64);
    asm volatile("s_waitcnt vmcnt(4)" ::: "memory");  // B-ks0, A-ks0 landed; ks1 in flight
    __builtin_amdgcn_s_barrier();

    int4v bf[4];

#define PHASE(KS, MH, SBASE, SRC, SOFFK, DOVM)                                             \
    do {                                                                                   \
        if ((MH) == 0) {                                                                   \
            _Pragma("unroll") for (int n = 0; n < 4; ++n)                                  \
                bf[n] = *(const int4v*)(BB + ((KS)*16 + wc * 4 + n) * 1024 + lane * 16);   \
        }                                                                                  \
        int4v af[4];                                                                       \
        _Pragma("unroll") for (int mi = 0; mi < 4; ++mi)                                   \
            af[mi] = *(const int4v*)(BA + ((KS)*16 + wr * 8 + (MH)*4 + mi) * 1024 +        \
                                     lane * 16);                                           \
        STAGEU((SBASE), (SRC), (SOFFK));                                                   \
        if (DOVM) asm volatile("s_waitcnt vmcnt(4)" ::: "memory");                         \
        __builtin_amdgcn_s_barrier();                                                      \
        __builtin_amdgcn_s_setprio(1);                                                     \
        _Pragma("unroll") for (int mi = 0; mi < 4; ++mi)                                   \
            _Pragma("unroll") for (int n = 0; n < 4; ++n)                                  \
                acc[(MH)*4 + mi][n] = __builtin_amdgcn_mfma_i32_16x16x64_i8(               \
                    af[mi], bf[n], acc[(MH)*4 + mi][n], 0, 0, 0);                          \
        __builtin_amdgcn_s_setprio(0);                                                     \
        __builtin_amdgcn_s_barrier();                                                      \
    } while (0)

#pragma unroll 1
    for (int u = 0; u < NT; ++u) {
        const int buf = u & 1;
        const signed char* BA = &lsA[buf][0];
        const signed char* BB = &lsB[buf][0];
        signed char* SA = &lsA[buf ^ 1][0];
        signed char* SB = &lsB[buf ^ 1][0];
        const size_t off1 = (size_t)((u + 1) & (NT - 1)) * 128;  // wrap: redundant tail restage

        PHASE(0, 0, SB, bSrc, off1, 0);
        PHASE(0, 1, SA, aSrc, off1, 1);
        PHASE(1, 0, SB + 16384, bSrc, off1 + 64, 0);
        PHASE(1, 1, SA + 16384, aSrc, off1 + 64, 1);
    }
#undef PHASE
#undef STAGEU

    // epilogue: C/D frag layout col=lane&15, row=(lane>>4)*4+reg
    const int rgrp = (lane >> 4) * 4;
    float wsv[4];
#pragma unroll
    for (int n = 0; n < 4; ++n) wsv[n] = wsc[bcol + wc * 64 + n * 16 + (lane & 15)];
#pragma unroll
    for (int m = 0; m < 8; ++m) {
#pragma unroll
        for (int r = 0; r < 4; ++r) {
            const int row = brow + wr * 128 + m * 16 + rgrp + r;
            const float xsv = xs[row];
            const size_t base = (size_t)row * N + bcol + wc * 64 + (lane & 15);
#pragma unroll
            for (int n = 0; n < 4; ++n)
                C[base + n * 16] = (float)acc[m][n][r] * (xsv * wsv[n]);
        }
    }
}

extern "C" void kernel_launch(void* const* d_in, const int* in_sizes, int n_in,
                              void* d_out, int out_size, void* d_ws, size_t ws_size,
                              hipStream_t stream) {
    const float* x = (const float*)d_in[0];
    const float* w = (const float*)d_in[1];
    float* out = (float*)d_out;

    const int K = 4096;
    const int M = in_sizes[0] / K;   // 8192
    const int N = in_sizes[1] / K;   // 11008

    signed char* x8 = (signed char*)d_ws;
    signed char* w8 = x8 + (size_t)M * K;
    float* xscales = (float*)(w8 + (size_t)N * K);
    float* wscales = xscales + M;

    quant_rows_k<<<M, 256, 0, stream>>>(x, x8, xscales);
    quant_rows_k<<<N, 256, 0, stream>>>(w, w8, wscales);
    const int nwg = (M / 256) * (N / 256);   // 32*43 = 1376 = 8*172
    gemm_i8_fp<<<nwg, 512, 0, stream>>>(x8, w8, xscales, wscales, out);
}